// Round 12
// baseline (110.235 us; speedup 1.0000x reference)
//
#include <hip/hip_runtime.h>
#include <math.h>

#define NHEAD 8

typedef __fp16 half2v __attribute__((ext_vector_type(2)));

// DPP-based add: v += lane-permuted(v). VALU pipe, no LDS traffic.
template <int CTRL>
__device__ __forceinline__ float dpp_add(float v) {
    int r = __builtin_amdgcn_mov_dpp(__float_as_int(v), CTRL, 0xF, 0xF, false);
    return v + __int_as_float(r);
}

// xor16 pair-sum via v_permlane16_swap_b32 (VALU pipe). Copy generated INSIDE asm with
// early-clobber so regalloc cannot coalesce (R8 failure). Validated in R9 (absmax 9.8e-4).
__device__ __forceinline__ float swap16_add(float v) {
    int a = __float_as_int(v);
    int b;
    asm volatile("v_mov_b32 %1, %0\n\t"
                 "s_nop 1\n\t"
                 "v_permlane16_swap_b32 %0, %1\n\t"
                 "s_nop 1"
                 : "+v"(a), "=&v"(b));
    return __int_as_float(a) + __int_as_float(b);
}
__device__ __forceinline__ float swap32_add(float v) {
    int a = __float_as_int(v);
    int b;
    asm volatile("v_mov_b32 %1, %0\n\t"
                 "s_nop 1\n\t"
                 "v_permlane32_swap_b32 %0, %1\n\t"
                 "s_nop 1"
                 : "+v"(a), "=&v"(b));
    return __int_as_float(a) + __int_as_float(b);
}

// full 64-lane broadcast-reduce: all lanes end with the total sum. Pure VALU.
__device__ __forceinline__ float wave_allsum(float v) {
    v = dpp_add<0xB1>(v);   // quad_perm xor1
    v = dpp_add<0x4E>(v);   // quad_perm xor2
    v = dpp_add<0x141>(v);  // row_half_mirror (pairs within 8)
    v = dpp_add<0x140>(v);  // row_mirror (pairs 8-groups within 16)
    v = swap16_add(v);      // across 16-rows
    v = swap32_add(v);      // across 32-halves
    return v;
}

// ---------------- K_setup: wsc (with inline q projection) + segment bounds ----------------
__global__ void __launch_bounds__(256) k_setup(const float* __restrict__ query,
                                               const float* __restrict__ W_in,
                                               const float* __restrict__ b_in,
                                               const int* __restrict__ batch,
                                               float* __restrict__ wsc,
                                               int* __restrict__ seg_start,
                                               int* __restrict__ seg_end,
                                               int N, float scale) {
    const int g = blockIdx.x, t = threadIdx.x;
    if (g < 16) {
        __shared__ float qs4[64][4];
        __shared__ float qs[64];
        const int h = g >> 1, half = g & 1;
        {
            const int d = t & 63, qtr = t >> 6;
            const int row = h * 64 + d;
            const float4* wq = reinterpret_cast<const float4*>(W_in + (size_t)row * 512 + qtr * 128);
            const float4* qv = reinterpret_cast<const float4*>(query + qtr * 128);
            float a = 0.f;
#pragma unroll 8
            for (int i = 0; i < 32; ++i) {
                float4 w = wq[i], q = qv[i];
                a += w.x * q.x + w.y * q.y + w.z * q.z + w.w * q.w;
            }
            qs4[d][qtr] = a;
        }
        __syncthreads();
        if (t < 64) {
            const float s = qs4[t][0] + qs4[t][1] + qs4[t][2] + qs4[t][3];
            qs[t] = (s + b_in[h * 64 + t]) * scale;
        }
        __syncthreads();
        const int i = half * 256 + t;
        const float* Wk = W_in + (size_t)512 * 512;
        float a = 0.f;
#pragma unroll 8
        for (int d = 0; d < 64; ++d)
            a += qs[d] * Wk[(size_t)(h * 64 + d) * 512 + i];
        wsc[h * 512 + i] = a;
    } else {
        const int stride = (gridDim.x - 16) * 256;
        for (int n = (g - 16) * 256 + t; n < N; n += stride) {
            int b = batch[n];
            if (n == 0 || batch[n - 1] != b) seg_start[b] = n;
            if (n == N - 1 || batch[n + 1] != b) seg_end[b] = n + 1;
        }
    }
}

// ---------------- k_fused1: single-read scores + softmax-partial + weighted accumulation ----------------
// grid (B, nc). Block owns a row chunk of graph b; 4 waves split the chunk. Lane owns cols
// [8*lane, 8*lane+8). Per row: f16-packed dot (v_dot2) -> all-VALU butterfly (all lanes get
// score) -> e=exp(s) -> acc[h][j] += e[h]*x[j]. x read ONCE; no main-loop barriers.
// Partial numerators/denominators per chunk (no-max exp is additive; validated R3-R9).
// VGPR diet: f16 weights (32), single-row pipeline (3 rows staged), 32KB LDS 2-chunk merge.
__global__ void __launch_bounds__(256, 3) k_fused1(const float* __restrict__ x,
                                                   const float* __restrict__ wsc,
                                                   const int* __restrict__ seg_start,
                                                   const int* __restrict__ seg_end,
                                                   float* __restrict__ xp_part,
                                                   float* __restrict__ denom_part,
                                                   int nc) {
    __shared__ float mrg[4][32][64];  // 32 KB: heads 0-3 pass, then heads 4-7
    __shared__ float dsum[4][NHEAD];
    const int b = blockIdx.x, c = blockIdx.y, t = threadIdx.x;
    const int lane = t & 63, w = t >> 6;
    const int s0 = seg_start[b], s1 = seg_end[b];
    const int len = s1 - s0;
    const int clen = (len + nc - 1) / nc;
    const int c0r = s0 + c * clen;
    const int c1r = min(s1, c0r + clen);
    const int wlen = (c1r - c0r + 3) >> 2;
    const int r0 = c0r + w * wlen;
    const int r1 = min(c1r, r0 + wlen);

    // f16-packed score weights: 8 heads x 4 half2 (8 cols) = 32 VGPRs
    half2v wh[NHEAD][4];
#pragma unroll
    for (int h = 0; h < NHEAD; ++h) {
        const float4 wa = *reinterpret_cast<const float4*>(wsc + h * 512 + lane * 8);
        const float4 wb = *reinterpret_cast<const float4*>(wsc + h * 512 + lane * 8 + 4);
        wh[h][0] = __builtin_amdgcn_cvt_pkrtz(wa.x, wa.y);
        wh[h][1] = __builtin_amdgcn_cvt_pkrtz(wa.z, wa.w);
        wh[h][2] = __builtin_amdgcn_cvt_pkrtz(wb.x, wb.y);
        wh[h][3] = __builtin_amdgcn_cvt_pkrtz(wb.z, wb.w);
    }

    float acc[NHEAD][8];
#pragma unroll
    for (int h = 0; h < NHEAD; ++h)
#pragma unroll
        for (int j = 0; j < 8; ++j) acc[h][j] = 0.f;
    float dacc[NHEAD];
#pragma unroll
    for (int h = 0; h < NHEAD; ++h) dacc[h] = 0.f;

    const float* xl = x + lane * 8;
#define LD0(r) (*reinterpret_cast<const float4*>(xl + (size_t)(r) * 512))
#define LD1(r) (*reinterpret_cast<const float4*>(xl + (size_t)(r) * 512 + 4))

    // single-row loop, 2-row lookahead (3 rows staged = 24 VGPR)
    float4 a0, a1, n0, n1;
    if (r0 + 0 < r1) { a0 = LD0(r0 + 0); a1 = LD1(r0 + 0); }
    if (r0 + 1 < r1) { n0 = LD0(r0 + 1); n1 = LD1(r0 + 1); }

    for (int r = r0; r < r1; ++r) {
        const float4 c0 = a0, c1 = a1;
        a0 = n0; a1 = n1;
        if (r + 2 < r1) { n0 = LD0(r + 2); n1 = LD1(r + 2); }

        // pack row to f16 (4 insts)
        const half2v xh0 = __builtin_amdgcn_cvt_pkrtz(c0.x, c0.y);
        const half2v xh1 = __builtin_amdgcn_cvt_pkrtz(c0.z, c0.w);
        const half2v xh2 = __builtin_amdgcn_cvt_pkrtz(c1.x, c1.y);
        const half2v xh3 = __builtin_amdgcn_cvt_pkrtz(c1.z, c1.w);

        float e[NHEAD];
#pragma unroll
        for (int h = 0; h < NHEAD; ++h) {
            float d = __builtin_amdgcn_fdot2(xh0, wh[h][0], 0.f, false);
            d = __builtin_amdgcn_fdot2(xh1, wh[h][1], d, false);
            d = __builtin_amdgcn_fdot2(xh2, wh[h][2], d, false);
            d = __builtin_amdgcn_fdot2(xh3, wh[h][3], d, false);
            e[h] = __expf(wave_allsum(d));
        }
#pragma unroll
        for (int h = 0; h < NHEAD; ++h) {
            dacc[h] += e[h];
            acc[h][0] += e[h] * c0.x; acc[h][1] += e[h] * c0.y;
            acc[h][2] += e[h] * c0.z; acc[h][3] += e[h] * c0.w;
            acc[h][4] += e[h] * c1.x; acc[h][5] += e[h] * c1.y;
            acc[h][6] += e[h] * c1.z; acc[h][7] += e[h] * c1.w;
        }
    }
#undef LD0
#undef LD1

    // epilogue: two-chunk LDS merge (heads 0-3, then 4-7), 32 KB buffer
    float* pb = xp_part + (size_t)(b * nc + c) * (NHEAD * 512);
    if (lane == 0) {
#pragma unroll
        for (int h = 0; h < NHEAD; ++h) dsum[w][h] = dacc[h];
    }
#pragma unroll
    for (int h = 0; h < 4; ++h)
#pragma unroll
        for (int j = 0; j < 8; ++j)
            mrg[w][h * 8 + j][lane] = acc[h][j];
    __syncthreads();
    {
        const int c0i = 2 * t;
        const int lsrc = c0i >> 3, slot = c0i & 7;
#pragma unroll
        for (int h = 0; h < 4; ++h) {
            float num0 = 0.f, num1 = 0.f;
#pragma unroll
            for (int g = 0; g < 4; ++g) {
                num0 += mrg[g][h * 8 + slot][lsrc];
                num1 += mrg[g][h * 8 + slot + 1][lsrc];
            }
            float2 o = {num0, num1};
            *reinterpret_cast<float2*>(pb + (size_t)h * 512 + c0i) = o;
        }
    }
    __syncthreads();
#pragma unroll
    for (int h = 4; h < NHEAD; ++h)
#pragma unroll
        for (int j = 0; j < 8; ++j)
            mrg[w][(h - 4) * 8 + j][lane] = acc[h][j];
    __syncthreads();
    {
        const int c0i = 2 * t;
        const int lsrc = c0i >> 3, slot = c0i & 7;
#pragma unroll
        for (int h = 4; h < NHEAD; ++h) {
            float num0 = 0.f, num1 = 0.f;
#pragma unroll
            for (int g = 0; g < 4; ++g) {
                num0 += mrg[g][(h - 4) * 8 + slot][lsrc];
                num1 += mrg[g][(h - 4) * 8 + slot + 1][lsrc];
            }
            float2 o = {num0, num1};
            *reinterpret_cast<float2*>(pb + (size_t)h * 512 + c0i) = o;
        }
    }
    if (t < NHEAD)
        denom_part[(b * nc + c) * NHEAD + t] = dsum[0][t] + dsum[1][t] + dsum[2][t] + dsum[3][t];
}

// ---------------- k_merge: xp[b,h,:] = (sum_c part[b,c,h,:]) / (sum_c denom[b,c,h]) ----------------
__global__ void __launch_bounds__(256) k_merge(const float* __restrict__ xp_part,
                                               const float* __restrict__ denom_part,
                                               float* __restrict__ xp, int nc) {
    const int b = blockIdx.x, t = threadIdx.x;
    __shared__ float rd[NHEAD];
    if (t < NHEAD) {
        float d = 0.f;
        for (int c = 0; c < nc; ++c) d += denom_part[(b * nc + c) * NHEAD + t];
        rd[t] = 1.f / d;
    }
    __syncthreads();
    const float2* src = reinterpret_cast<const float2*>(xp_part + (size_t)b * nc * NHEAD * 512);
    float2* dst = reinterpret_cast<float2*>(xp + (size_t)b * NHEAD * 512);
#pragma unroll
    for (int i = 0; i < 8; ++i) {
        const int idx = i * 256 + t;          // float2 index within [8][256]
        const int h = idx >> 8;
        float2 s = src[idx];
        for (int c = 1; c < nc; ++c) {
            const float2 v = src[(size_t)c * NHEAD * 256 + idx];
            s.x += v.x; s.y += v.y;
        }
        const float r = rd[h];
        s.x *= r; s.y *= r;
        dst[idx] = s;
    }
}

// ---------------- 4-wave K-split GEMM: C[m,n] = sum_k A[m,k]*B[n,k] + bias[n] ----------------
__global__ void __launch_bounds__(256) k_gemm_tn4w(const float* __restrict__ A, int lda, int zA,
                                                   const float* __restrict__ Bm, int ldb, int zB,
                                                   const float* __restrict__ bias, int zBias,
                                                   float* __restrict__ C, int ldc, int zC, int K) {
    __shared__ float As[4][32][36]; // [wave][kk][m]
    __shared__ float Bs[4][32][36]; // [wave][kk][n]
    __shared__ float red[4][32][32];
    const int z = blockIdx.z;
    A += (size_t)z * zA;
    Bm += (size_t)z * zB;
    bias += (size_t)z * zBias;
    C += (size_t)z * zC;
    const int m0 = blockIdx.x * 32, n0 = blockIdx.y * 32;
    const int t = threadIdx.x;
    const int w = t >> 6, lane = t & 63;
    const int row = lane >> 1, c0 = (lane & 1) * 16;
    const int ty = lane >> 3, tx = lane & 7;
    const int Kw = K >> 2;
    const int kw0 = w * Kw;
    float c[4][4];
#pragma unroll
    for (int i = 0; i < 4; ++i)
#pragma unroll
        for (int j = 0; j < 4; ++j) c[i][j] = 0.f;

    for (int kt = 0; kt < Kw; kt += 32) {
        const int k0 = kw0 + kt;
        const float* Ar = A + (size_t)(m0 + row) * lda + k0 + c0;
        const float* Br = Bm + (size_t)(n0 + row) * ldb + k0 + c0;
        float4 a4[4], b4[4];
#pragma unroll
        for (int j = 0; j < 4; ++j) {
            a4[j] = *reinterpret_cast<const float4*>(Ar + j * 4);
            b4[j] = *reinterpret_cast<const float4*>(Br + j * 4);
        }
#pragma unroll
        for (int j = 0; j < 4; ++j) {
            As[w][c0 + j * 4 + 0][row] = a4[j].x;
            As[w][c0 + j * 4 + 1][row] = a4[j].y;
            As[w][c0 + j * 4 + 2][row] = a4[j].z;
            As[w][c0 + j * 4 + 3][row] = a4[j].w;
            Bs[w][c0 + j * 4 + 0][row] = b4[j].x;
            Bs[w][c0 + j * 4 + 1][row] = b4[j].y;
            Bs[w][c0 + j * 4 + 2][row] = b4[j].z;
            Bs[w][c0 + j * 4 + 3][row] = b4[j].w;
        }
#pragma unroll
        for (int kk = 0; kk < 32; ++kk) {
            float4 av = *reinterpret_cast<const float4*>(&As[w][kk][ty * 4]);
            float4 bv = *reinterpret_cast<const float4*>(&Bs[w][kk][tx * 4]);
            c[0][0] += av.x * bv.x; c[0][1] += av.x * bv.y; c[0][2] += av.x * bv.z; c[0][3] += av.x * bv.w;
            c[1][0] += av.y * bv.x; c[1][1] += av.y * bv.y; c[1][2] += av.y * bv.z; c[1][3] += av.y * bv.w;
            c[2][0] += av.z * bv.x; c[2][1] += av.z * bv.y; c[2][2] += av.z * bv.z; c[2][3] += av.z * bv.w;
            c[3][0] += av.w * bv.x; c[3][1] += av.w * bv.y; c[3][2] += av.w * bv.z; c[3][3] += av.w * bv.w;
        }
    }
#pragma unroll
    for (int i = 0; i < 4; ++i)
#pragma unroll
        for (int j = 0; j < 4; ++j) red[w][ty * 4 + i][tx * 4 + j] = c[i][j];
    __syncthreads();
    const int r = t >> 3, cc = (t & 7) * 4;
    float4 s = {0.f, 0.f, 0.f, 0.f};
#pragma unroll
    for (int g = 0; g < 4; ++g) {
        const float4 v = *reinterpret_cast<const float4*>(&red[g][r][cc]);
        s.x += v.x; s.y += v.y; s.z += v.z; s.w += v.w;
    }
    const float4 bv4 = *reinterpret_cast<const float4*>(bias + n0 + cc);
    float4 o = {s.x + bv4.x, s.y + bv4.y, s.z + bv4.z, s.w + bv4.w};
    *reinterpret_cast<float4*>(C + (size_t)(m0 + r) * ldc + n0 + cc) = o;
}

extern "C" void kernel_launch(void* const* d_in, const int* in_sizes, int n_in,
                              void* d_out, int out_size, void* d_ws, size_t ws_size,
                              hipStream_t stream) {
    const float* x     = (const float*)d_in[0];
    const int*   batch = (const int*)d_in[1];
    const float* query = (const float*)d_in[3];
    const float* W_in  = (const float*)d_in[4];
    const float* b_in  = (const float*)d_in[5];
    const float* W_out = (const float*)d_in[6];
    const float* b_out = (const float*)d_in[7];
    float* out = (float*)d_out;

    const int D = in_sizes[3];         // 512
    const int N = in_sizes[0] / D;     // 131072
    const int B = out_size / D;        // 512 graphs
    const int dh = D / NHEAD;          // 64
    const float scale = 1.0f / sqrtf((float)dh);

    // workspace carve (floats)
    float* wsf       = (float*)d_ws;
    float* wsc       = wsf;                                  // 4096
    float* xp        = wsc + NHEAD * 512;                    // B*4096
    float* pooled    = xp + (size_t)B * NHEAD * 512;         // B*512
    float* denom_ws  = pooled + (size_t)B * 512;             // B*4*H max
    int*   seg_start = (int*)(denom_ws + (size_t)B * 4 * NHEAD); // B
    int*   seg_end   = seg_start + B;                        // B
    float* tail      = (float*)(seg_end + B);

    // chunk count: prefer 3 (grid 1536 = 2 balanced rounds at 3 blocks/CU)
    const size_t usedFloats = (size_t)(tail - wsf);
    const size_t avail = ws_size / 4 - usedFloats;
    int nc = 1;
    float* xp_part = xp;  // nc==1: partials ARE xp (merge normalizes in place)
    if (avail >= (size_t)B * 3 * NHEAD * 512) {
        nc = 3;
        xp_part = tail;
    }

    // K0: wsc (inline q) + segment bounds
    k_setup<<<16 + 256, 256, 0, stream>>>(query, W_in, b_in, batch, wsc,
                                          seg_start, seg_end, N, scale);

    // K1: fused single-read scores + softmax partials + weighted accumulation
    k_fused1<<<dim3(B, nc), 256, 0, stream>>>(x, wsc, seg_start, seg_end,
                                              xp_part, denom_ws, nc);

    // K2: merge chunk partials, normalize
    k_merge<<<B, 256, 0, stream>>>(xp_part, denom_ws, xp, nc);

    // K3: pooled[b, h*64+j] = sum_i xp[b,h,i] * W_v[h*64+j, i] + b_v[h*64+j]
    k_gemm_tn4w<<<dim3(B / 32, dh / 32, NHEAD), 256, 0, stream>>>(
        xp, NHEAD * 512, 512,
        W_in + (size_t)2 * D * D, D, dh * D,
        b_in + 2 * D, dh,
        pooled, D, dh, D);

    // K4: out = pooled @ W_out^T + b_out
    k_gemm_tn4w<<<dim3(B / 32, D / 32, 1), 256, 0, stream>>>(
        pooled, D, 0,
        W_out, D, 0,
        b_out, 0,
        out, D, 0, D);
}